// Round 1
// baseline (454.868 us; speedup 1.0000x reference)
//
#include <hip/hip_runtime.h>
#include <math.h>

// Problem constants (from the reference): V=100000, D=300, B=16384, NCTX=10, NNEG=20
#define DIM   300
#define NCTX  10
#define NNEG  20
#define BLOCK 256   // 4 waves

__device__ __forceinline__ float log_sigmoid(float x) {
    // stable: min(x,0) - log1p(exp(-|x|))
    return fminf(x, 0.0f) - log1pf(expf(-fabsf(x)));
}

__global__ __launch_bounds__(BLOCK) void cbow_loss_kernel(
    const int*   __restrict__ ctx,     // [B, NCTX]
    const int*   __restrict__ center,  // [B]
    const int*   __restrict__ neg,     // [B, NNEG]
    const float* __restrict__ in_w,    // [V, D]
    const float* __restrict__ out_w,   // [V, D]
    float*       __restrict__ out,     // [1], zeroed before launch
    float inv_b)
{
    __shared__ float ctx_mean[DIM];
    __shared__ float wave_sum[4];
    __shared__ int   widx[NCTX + 1 + NNEG];   // 10 ctx, 1 center, 20 neg

    const int b   = blockIdx.x;
    const int tid = threadIdx.x;

    // Load the 31 word indices for this sample into LDS.
    if (tid < NCTX)                    widx[tid] = ctx[b * NCTX + tid];
    else if (tid == NCTX)              widx[NCTX] = center[b];
    else if (tid < NCTX + 1 + NNEG)    widx[tid] = neg[b * NNEG + (tid - NCTX - 1)];
    __syncthreads();

    // Phase 1: mean-pool the 10 context rows into LDS. Coalesced: consecutive
    // threads read consecutive elements of each 1200B row.
    for (int d = tid; d < DIM; d += BLOCK) {
        float s = 0.0f;
        #pragma unroll
        for (int j = 0; j < NCTX; ++j)
            s += in_w[(long long)widx[j] * DIM + d];
        ctx_mean[d] = s * (1.0f / NCTX);
    }
    __syncthreads();

    const int wave = tid >> 6;
    const int lane = tid & 63;

    // Phase 2: 21 dot products (i=0 is positive, 1..20 negatives), round-robin
    // across the 4 waves. Each wave's 64 lanes stride the 300-dim row.
    float local = 0.0f;
    for (int i = wave; i < 1 + NNEG; i += 4) {
        const float* row = out_w + (long long)widx[NCTX + i] * DIM;
        float p = 0.0f;
        for (int d = lane; d < DIM; d += 64)
            p += row[d] * ctx_mean[d];
        // 64-lane butterfly reduce (wave = 64 on CDNA4, no mask arg)
        #pragma unroll
        for (int off = 32; off > 0; off >>= 1)
            p += __shfl_down(p, off, 64);
        if (lane == 0)
            local += log_sigmoid(i == 0 ? p : -p);
    }
    if (lane == 0) wave_sum[wave] = local;
    __syncthreads();

    if (tid == 0) {
        float t = wave_sum[0] + wave_sum[1] + wave_sum[2] + wave_sum[3];
        // loss = -mean_b(...): each block contributes -sum_b / B
        atomicAdd(out, -t * inv_b);
    }
}

extern "C" void kernel_launch(void* const* d_in, const int* in_sizes, int n_in,
                              void* d_out, int out_size, void* d_ws, size_t ws_size,
                              hipStream_t stream) {
    const int*   ctx    = (const int*)  d_in[0];  // [B, NCTX]
    const int*   center = (const int*)  d_in[1];  // [B]
    const int*   neg    = (const int*)  d_in[2];  // [B, NNEG]
    const float* in_w   = (const float*)d_in[3];  // [V, D]
    const float* out_w  = (const float*)d_in[4];  // [V, D]
    float*       out    = (float*)d_out;

    const int B = in_sizes[1];  // center_word is [B]

    // d_out is poisoned to 0xAA before every timed replay; zero it on-stream.
    hipMemsetAsync(out, 0, sizeof(float), stream);

    cbow_loss_kernel<<<B, BLOCK, 0, stream>>>(ctx, center, neg, in_w, out_w,
                                              out, 1.0f / (float)B);
}

// Round 2
// 429.484 us; speedup vs baseline: 1.0591x; 1.0591x over previous
//
#include <hip/hip_runtime.h>
#include <math.h>

// V=100000, D=300, B=16384, NCTX=10, NNEG=20
#define DIM    300
#define CH     75          // DIM/4 float4 chunks per row (1200 B, 16B-aligned)
#define NCTX   10
#define NNEG   20
#define NROWS  (1 + NNEG)  // 21 out-embed rows: [0]=center, [1..20]=negatives
#define BLOCK  256         // 4 waves per block, 1 sample per block

__device__ __forceinline__ float log_sigmoid(float x) {
    // stable: min(x,0) - log1p(exp(-|x|))
    return fminf(x, 0.0f) - log1pf(expf(-fabsf(x)));
}

__device__ __forceinline__ float dot4(float4 a, float4 b) {
    return a.x * b.x + a.y * b.y + a.z * b.z + a.w * b.w;
}

__device__ __forceinline__ float4 add4(float4 a, float4 b) {
    return make_float4(a.x + b.x, a.y + b.y, a.z + b.z, a.w + b.w);
}

__global__ __launch_bounds__(BLOCK) void cbow_loss_kernel(
    const int*   __restrict__ ctx,     // [B, NCTX]
    const int*   __restrict__ center,  // [B]
    const int*   __restrict__ neg,     // [B, NNEG]
    const float* __restrict__ in_w,    // [V, D]
    const float* __restrict__ out_w,   // [V, D]
    float*       __restrict__ out,     // [1], zeroed on-stream before launch
    float inv_b)
{
    __shared__ int    widx[NCTX + NROWS];  // 10 ctx, then 21 out rows
    __shared__ float4 ctxp[4][CH];         // per-wave partial ctx sums
    __shared__ float4 mean4[CH];
    __shared__ float  wave_sum[4];

    const int b    = blockIdx.x;
    const int tid  = threadIdx.x;
    const int wave = tid >> 6;
    const int lane = tid & 63;

    if (tid < NCTX)                widx[tid] = ctx[b * NCTX + tid];
    else if (tid == NCTX)          widx[tid] = center[b];
    else if (tid < NCTX + NROWS)   widx[tid] = neg[b * NNEG + (tid - NCTX - 1)];
    __syncthreads();

    // ---- Prefetch phase-2 rows into registers BEFORE phase-1 work, so all
    // 31 row-gathers of this block are in flight at once. Wave w owns out
    // rows i = w, w+4, ... (wave0: 6 rows; waves1-3: 5 rows). Each lane holds
    // chunk `lane` (all) and chunk `64+lane` (lanes 0..10 only).
    float4 r0[6], r1[6];
    #pragma unroll
    for (int k = 0; k < 6; ++k) {
        const int i = wave + 4 * k;
        if (i < NROWS) {
            const float4* row = (const float4*)(out_w + (long long)widx[NCTX + i] * DIM);
            r0[k] = row[lane];
            r1[k] = (lane < CH - 64) ? row[64 + lane] : make_float4(0.f, 0.f, 0.f, 0.f);
        }
    }

    // ---- Phase 1: mean-pool ctx rows. Wave w accumulates rows j = w, w+4, ...
    float4 a0 = make_float4(0.f, 0.f, 0.f, 0.f);
    float4 a1 = make_float4(0.f, 0.f, 0.f, 0.f);
    for (int j = wave; j < NCTX; j += 4) {
        const float4* row = (const float4*)(in_w + (long long)widx[j] * DIM);
        a0 = add4(a0, row[lane]);
        if (lane < CH - 64) a1 = add4(a1, row[64 + lane]);
    }
    ctxp[wave][lane] = a0;
    if (lane < CH - 64) ctxp[wave][64 + lane] = a1;
    __syncthreads();

    if (tid < CH) {
        float4 s = add4(add4(ctxp[0][tid], ctxp[1][tid]),
                        add4(ctxp[2][tid], ctxp[3][tid]));
        mean4[tid] = make_float4(s.x * (1.f / NCTX), s.y * (1.f / NCTX),
                                 s.z * (1.f / NCTX), s.w * (1.f / NCTX));
    }
    __syncthreads();

    // Row-invariant mean chunks: read LDS once per wave, not per row.
    const float4 m0 = mean4[lane];
    const float4 m1 = (lane < CH - 64) ? mean4[64 + lane]
                                       : make_float4(0.f, 0.f, 0.f, 0.f);

    // ---- Phase 2: per-lane partial dots for this wave's rows (ILP), then
    // six butterfly steps with the 5-6 independent chains interleaved.
    float p[6];
    #pragma unroll
    for (int k = 0; k < 6; ++k) {
        const int i = wave + 4 * k;
        p[k] = (i < NROWS) ? dot4(r0[k], m0) + dot4(r1[k], m1) : 0.f;
    }
    #pragma unroll
    for (int off = 32; off > 0; off >>= 1) {
        #pragma unroll
        for (int k = 0; k < 6; ++k)
            p[k] += __shfl_down(p[k], off, 64);
    }

    if (lane == 0) {
        float local = 0.f;
        #pragma unroll
        for (int k = 0; k < 6; ++k) {
            const int i = wave + 4 * k;
            if (i < NROWS)
                local += log_sigmoid(i == 0 ? p[k] : -p[k]);
        }
        wave_sum[wave] = local;
    }
    __syncthreads();

    if (tid == 0) {
        float t = wave_sum[0] + wave_sum[1] + wave_sum[2] + wave_sum[3];
        atomicAdd(out, -t * inv_b);   // loss = -mean_b(...)
    }
}

extern "C" void kernel_launch(void* const* d_in, const int* in_sizes, int n_in,
                              void* d_out, int out_size, void* d_ws, size_t ws_size,
                              hipStream_t stream) {
    const int*   ctx    = (const int*)  d_in[0];
    const int*   center = (const int*)  d_in[1];
    const int*   neg    = (const int*)  d_in[2];
    const float* in_w   = (const float*)d_in[3];
    const float* out_w  = (const float*)d_in[4];
    float*       out    = (float*)d_out;

    const int B = in_sizes[1];  // center_word is [B]

    hipMemsetAsync(out, 0, sizeof(float), stream);
    cbow_loss_kernel<<<B, BLOCK, 0, stream>>>(ctx, center, neg, in_w, out_w,
                                              out, 1.0f / (float)B);
}

// Round 3
// 299.730 us; speedup vs baseline: 1.5176x; 1.4329x over previous
//
#include <hip/hip_runtime.h>
#include <math.h>

// V=100000, D=300, B=16384, NCTX=10, NNEG=20
#define DIM    300
#define CH     75           // float4 chunks per row (1200 B, 16B-aligned)
#define NCTX   10
#define NNEG   20
#define NROWS  (1 + NNEG)   // 21 out rows: [0]=center, [1..20]=negatives
#define BLOCK  256          // 4 waves/block, ONE WAVE PER SAMPLE
#define G      7            // out-rows per batch (3 batches of 7)

__device__ __forceinline__ float log_sigmoid(float x) {
    return fminf(x, 0.0f) - log1pf(expf(-fabsf(x)));
}
__device__ __forceinline__ float dot4(float4 a, float4 b) {
    return a.x * b.x + a.y * b.y + a.z * b.z + a.w * b.w;
}
__device__ __forceinline__ float4 add4(float4 a, float4 b) {
    return make_float4(a.x + b.x, a.y + b.y, a.z + b.z, a.w + b.w);
}

__global__ __launch_bounds__(BLOCK) void cbow_loss_kernel(
    const int*   __restrict__ ctx,     // [B, NCTX]
    const int*   __restrict__ center,  // [B]
    const int*   __restrict__ neg,     // [B, NNEG]
    const float* __restrict__ in_w,    // [V, D]
    const float* __restrict__ out_w,   // [V, D]
    float*       __restrict__ out,     // [1], zeroed on-stream
    int B, float inv_b)
{
    __shared__ float wsum[4];

    const int tid  = threadIdx.x;
    const int wave = tid >> 6;
    const int lane = tid & 63;
    const int b    = blockIdx.x * 4 + wave;   // one sample per wave

    float loss = 0.f;
    if (b < B) {
        // Each lane loads one of the 31 word indices; rows are addressed via
        // wave-uniform __shfl broadcasts (no LDS, no barriers in hot path).
        int myidx = 0;
        if (lane < NCTX)                 myidx = ctx[b * NCTX + lane];
        else if (lane == NCTX)           myidx = center[b];
        else if (lane < NCTX + NROWS)    myidx = neg[b * NNEG + (lane - NCTX - 1)];

        // Chunk ownership: chunk c1=lane (always valid), chunk c2=64+lane
        // (valid only for lanes 0..10). Loads are unconditional (clamped addr,
        // same-line broadcast for invalid lanes) so nothing blocks pipelining;
        // validity handled by zeroing m1's weight.
        const int   c1 = lane;
        const int   c2 = (64 + lane < CH) ? 64 + lane : CH - 1;
        const float w1 = (64 + lane < CH) ? 1.f : 0.f;

        // ---- Phase 1: ctx mean, fully in registers. 20 independent loads.
        float4 a0 = make_float4(0.f, 0.f, 0.f, 0.f);
        float4 a1 = make_float4(0.f, 0.f, 0.f, 0.f);
        #pragma unroll
        for (int j = 0; j < NCTX; ++j) {
            const int w = __shfl(myidx, j, 64);
            const float4* row = (const float4*)(in_w + (long long)w * DIM);
            a0 = add4(a0, row[c1]);
            a1 = add4(a1, row[c2]);
        }
        const float s0 = 1.f / NCTX;
        const float s1 = w1 / NCTX;    // zeroes invalid second chunks
        const float4 m0 = make_float4(a0.x * s0, a0.y * s0, a0.z * s0, a0.w * s0);
        const float4 m1 = make_float4(a1.x * s1, a1.y * s1, a1.z * s1, a1.w * s1);

        // ---- Phase 2: 21 dots in 3 batches of 7. 14 independent loads per
        // batch; unrolled so batch t+1 loads can overlap batch t reduction.
        #pragma unroll
        for (int t = 0; t < 3; ++t) {
            float4 r0[G], r1[G];
            #pragma unroll
            for (int k = 0; k < G; ++k) {
                const int w = __shfl(myidx, NCTX + t * G + k, 64);
                const float4* row = (const float4*)(out_w + (long long)w * DIM);
                r0[k] = row[c1];
                r1[k] = row[c2];
            }
            float p[G];
            #pragma unroll
            for (int k = 0; k < G; ++k)
                p[k] = dot4(r0[k], m0) + dot4(r1[k], m1);
            #pragma unroll
            for (int off = 32; off > 0; off >>= 1) {
                #pragma unroll
                for (int k = 0; k < G; ++k)
                    p[k] += __shfl_down(p[k], off, 64);
            }
            if (lane == 0) {
                #pragma unroll
                for (int k = 0; k < G; ++k) {
                    const int i = t * G + k;
                    loss += log_sigmoid(i == 0 ? p[k] : -p[k]);
                }
            }
        }
    }

    if (lane == 0) wsum[wave] = loss;
    __syncthreads();
    if (tid == 0)
        atomicAdd(out, -(wsum[0] + wsum[1] + wsum[2] + wsum[3]) * inv_b);
}

extern "C" void kernel_launch(void* const* d_in, const int* in_sizes, int n_in,
                              void* d_out, int out_size, void* d_ws, size_t ws_size,
                              hipStream_t stream) {
    const int*   ctx    = (const int*)  d_in[0];
    const int*   center = (const int*)  d_in[1];
    const int*   neg    = (const int*)  d_in[2];
    const float* in_w   = (const float*)d_in[3];
    const float* out_w  = (const float*)d_in[4];
    float*       out    = (float*)d_out;

    const int B = in_sizes[1];  // center_word is [B]

    hipMemsetAsync(out, 0, sizeof(float), stream);
    cbow_loss_kernel<<<(B + 3) / 4, BLOCK, 0, stream>>>(ctx, center, neg,
                                                        in_w, out_w, out,
                                                        B, 1.0f / (float)B);
}